// Round 6
// baseline (350.160 us; speedup 1.0000x reference)
//
#include <hip/hip_runtime.h>
#include <math.h>

// Problem constants
constexpr int B_  = 128;
constexpr int S_  = 256;
constexpr int D_  = 128;   // d_model
constexpr int H_  = 8;
constexpr int DK_ = 16;
constexpr int SK_ = 30;    // SAMPLE_K
constexpr int NT_ = 30;    // N_TOP

typedef short short8  __attribute__((ext_vector_type(8)));
typedef float floatx4 __attribute__((ext_vector_type(4)));

__device__ inline ushort bf16_rne(float f) {
    unsigned u = __float_as_uint(f);
    u += 0x7fffu + ((u >> 16) & 1u);
    return (ushort)(u >> 16);
}
__device__ inline float bf16_to_f(ushort h) {
    return __uint_as_float(((unsigned)h) << 16);
}

// ---------------------------------------------------------------------------
// K0: W prep + trig table (merged).  conv weights (o,i,t) fp32 -> [t][o][i]
//  bf16 hi/lo; lin_w -> bf16 hi/lo; rotary trig in double (bitwise-stable
//  across rounds -> top-k selection unchanged).
// ---------------------------------------------------------------------------
__global__ __launch_bounds__(256) void wprep_kernel(
    const float* __restrict__ wk, const float* __restrict__ wv,
    const float* __restrict__ lw,
    ushort* __restrict__ wk_hi, ushort* __restrict__ wk_lo,
    ushort* __restrict__ wv_hi,
    ushort* __restrict__ lw_hi, ushort* __restrict__ lw_lo,
    float* __restrict__ trig)
{
    int tid = blockIdx.x * 256 + threadIdx.x;   // 0 .. 163839 (grid 640)
    if (tid < 131072) {
        int which = tid >> 16;                  // 0 = k-conv, 1 = v-conv
        int oi = tid & 65535;                   // o*256 + i
        const float* src = (which ? wv : wk) + (size_t)oi * 7;
#pragma unroll
        for (int t = 0; t < 7; t++) {
            float f = src[t];
            ushort hi = bf16_rne(f);
            size_t dst = (size_t)t * 65536 + oi;
            if (which) {
                wv_hi[dst] = hi;
            } else {
                wk_hi[dst] = hi;
                wk_lo[dst] = bf16_rne(f - bf16_to_f(hi));
            }
        }
    } else if (tid < 147456) {
        int ec = tid - 131072;                  // e*128 + c
        float f = lw[ec];
        ushort hi = bf16_rne(f);
        lw_hi[ec] = hi;
        lw_lo[ec] = bf16_rne(f - bf16_to_f(hi));
    } else {
        int t2 = tid - 147456;                  // 0 .. 16383
        int f = t2 & 63, l = t2 >> 6;
        double freq = exp(((double)(-f) / 64.0) * 9.210340371976184); // ln(1e4)
        double ang  = (double)l * freq;
        trig[t2 * 2]     = (float)cos(ang);
        trig[t2 * 2 + 1] = (float)sin(ang);
    }
}

// ---------------------------------------------------------------------------
// K1: fused rotary + transpose + bf16 hi/lo convert.
//  Per block: (b, 64-l chunk).  q: rotary -> q_h (B,H,S,DK) fp32 directly.
//  k: rotary -> LDS tile -> transposed (B,D,S) bf16 hi/lo.
//  v: LDS tile -> transposed (B,D,S) bf16 hi.
//  Same trig + bf16_rne as R5 -> q_h/khi/klo bitwise identical.
// ---------------------------------------------------------------------------
__global__ __launch_bounds__(256) void rotcvt_kernel(
    const float* __restrict__ q, const float* __restrict__ k,
    const float* __restrict__ value, const float* __restrict__ trig,
    float* __restrict__ q_h,
    ushort* __restrict__ khi_t, ushort* __restrict__ klo_t,
    ushort* __restrict__ vhi_t)
{
    __shared__ float tile[64 * 132];   // 64 l x 128 d, pad 4
    int b  = blockIdx.x;
    int lc = blockIdx.y;               // l-chunk of 64
    int tid = threadIdx.x;

    // ---- phase q: rotary, direct write (no transpose needed) ----
    for (int s = tid; s < 2048; s += 256) {
        int l = s >> 5, c4 = s & 31;
        int lg = lc * 64 + l;
        float4 qv = *(const float4*)(q + (((size_t)b * 256) + lg) * 128 + c4 * 4);
        float4 tg = *(const float4*)(trig + ((size_t)lg * 64 + 2 * c4) * 2);
        float r0 = qv.x * tg.x - qv.y * tg.y;
        float i0 = qv.x * tg.y + qv.y * tg.x;
        float r1 = qv.z * tg.z - qv.w * tg.w;
        float i1 = qv.z * tg.w + qv.w * tg.z;
        int h = c4 >> 2, dk = (c4 & 3) * 4;
        *(float4*)(q_h + (((size_t)b * 8 + h) * 256 + lg) * 16 + dk) =
            make_float4(r0, i0, r1, i1);
    }

    // ---- phase k: rotary into LDS, transpose out as bf16 hi/lo ----
    for (int s = tid; s < 2048; s += 256) {
        int l = s >> 5, c4 = s & 31;
        int lg = lc * 64 + l;
        float4 kv = *(const float4*)(k + (((size_t)b * 256) + lg) * 128 + c4 * 4);
        float4 tg = *(const float4*)(trig + ((size_t)lg * 64 + 2 * c4) * 2);
        float r0 = kv.x * tg.x - kv.y * tg.y;
        float i0 = kv.x * tg.y + kv.y * tg.x;
        float r1 = kv.z * tg.z - kv.w * tg.w;
        float i1 = kv.z * tg.w + kv.w * tg.z;
        *(float4*)(tile + l * 132 + c4 * 4) = make_float4(r0, i0, r1, i1);
    }
    __syncthreads();
    {
        int d = tid >> 1, half = tid & 1;
        alignas(16) ushort hh[32], ll[32];
#pragma unroll
        for (int j = 0; j < 32; j++) {
            float f = tile[(half * 32 + j) * 132 + d];
            ushort hb = bf16_rne(f);
            hh[j] = hb;
            ll[j] = bf16_rne(f - bf16_to_f(hb));
        }
        size_t off = (((size_t)b * 128) + d) * 256 + lc * 64 + half * 32;
#pragma unroll
        for (int m = 0; m < 4; m++) ((uint4*)(khi_t + off))[m] = ((uint4*)hh)[m];
#pragma unroll
        for (int m = 0; m < 4; m++) ((uint4*)(klo_t + off))[m] = ((uint4*)ll)[m];
    }
    __syncthreads();

    // ---- phase v: no rotary, bf16 hi only ----
    for (int s = tid; s < 2048; s += 256) {
        int l = s >> 5, c4 = s & 31;
        *(float4*)(tile + l * 132 + c4 * 4) =
            *(const float4*)(value + (((size_t)b * 256) + lc * 64 + l) * 128 + c4 * 4);
    }
    __syncthreads();
    {
        int d = tid >> 1, half = tid & 1;
        alignas(16) ushort hh[32];
#pragma unroll
        for (int j = 0; j < 32; j++)
            hh[j] = bf16_rne(tile[(half * 32 + j) * 132 + d]);
        size_t off = (((size_t)b * 128) + d) * 256 + lc * 64 + half * 32;
#pragma unroll
        for (int m = 0; m < 4; m++) ((uint4*)(vhi_t + off))[m] = ((uint4*)hh)[m];
    }
}

// ---------------------------------------------------------------------------
// K2: fused causal-conv-as-MFMA-GEMM, v4 tiling.
//  Block = 64 o x 128 d, 4 waves split d (wave = 64 o x 32 d, po=4, nd=2):
//  per (ks2,t) per wave: 2(+2 lo) ds_read_b128 + 8 global 16B (shared by all
//  4 waves -> L1) -> 24 MFMAs (k) / 8 (v).  Per-CU LDS ~32k cyc < MFMA ~70k
//  cyc -> MFMA-bound.  Grid 128x4x2 = 1024 = 4 blocks/CU (LDS 38.6 KB).
//  Accumulation order per output identical to R5 -> k_h bitwise unchanged.
// ---------------------------------------------------------------------------
__global__ __launch_bounds__(256, 4) void conv4_kernel(
    const ushort* __restrict__ khi_t, const ushort* __restrict__ klo_t,
    const ushort* __restrict__ vhi_t,
    const ushort* __restrict__ wk_hi, const ushort* __restrict__ wk_lo,
    const ushort* __restrict__ wv_hi,
    const float* __restrict__ kbias, const float* __restrict__ vbias,
    float* __restrict__ k_h, float* __restrict__ v_h)
{
    constexpr int LI = 72;                 // 64 i + 8 pad (16B-aligned rows)
    __shared__ ushort xhi[134 * LI];
    __shared__ ushort xlo[134 * LI];

    const bool kp = (blockIdx.z == 0);
    const ushort* xhi_g = kp ? khi_t : vhi_t;
    const ushort* whi   = kp ? wk_hi : wv_hi;
    const float*  bias  = kp ? kbias : vbias;
    float* yh           = kp ? k_h : v_h;

    int b     = blockIdx.x;
    int obase = blockIdx.y * 64;
    int tid   = threadIdx.x;
    int lane  = tid & 63, dw = tid >> 6;   // wave owns 32-d slice
    int lm = lane & 15, kb = lane >> 4;
    int dbase = dw * 32;

    floatx4 acc[8];
#pragma unroll
    for (int i = 0; i < 8; i++) acc[i] = (floatx4){0.f, 0.f, 0.f, 0.f};

    // causal left pad (rows c<6 i.e. d<0): zero once, valid for all ic
    for (int idx = tid; idx < 6 * LI; idx += 256) { xhi[idx] = 0; xlo[idx] = 0; }

    const ushort* abase_h = xhi + (dbase + lm) * LI + kb * 8;
    const ushort* abase_l = xlo + (dbase + lm) * LI + kb * 8;

    for (int ic = 0; ic < 4; ic++) {
        __syncthreads();
        // stage 128 d-rows x 64 i: pure 16B copies from (B,D,S) layout
        for (int s = tid; s < 1024; s += 256) {
            int d = s >> 3, p = s & 7;
            size_t g = (((size_t)b * 128) + d) * 256 + ic * 64 + p * 8;
            *(short8*)(xhi + (d + 6) * LI + p * 8) = *(const short8*)(xhi_g + g);
            if (kp)
                *(short8*)(xlo + (d + 6) * LI + p * 8) = *(const short8*)(klo_t + g);
        }
        __syncthreads();
#pragma unroll
        for (int ks2 = 0; ks2 < 2; ks2++) {
            int ibase = ic * 64 + ks2 * 32 + kb * 8;
#pragma unroll
            for (int t = 0; t < 7; t++) {
                short8 xh[2], xl[2];
#pragma unroll
                for (int nd = 0; nd < 2; nd++) {
                    xh[nd] = *(const short8*)(abase_h + (nd * 16 + t) * LI + ks2 * 32);
                    if (kp) xl[nd] = *(const short8*)(abase_l + (nd * 16 + t) * LI + ks2 * 32);
                }
                short8 wh[4], wl[4];
#pragma unroll
                for (int po = 0; po < 4; po++) {
                    size_t woff = (size_t)t * 65536 + (size_t)(obase + po * 16 + lm) * 256 + ibase;
                    wh[po] = *(const short8*)(whi + woff);
                    if (kp) wl[po] = *(const short8*)(wk_lo + woff);
                }
#pragma unroll
                for (int po = 0; po < 4; po++) {
#pragma unroll
                    for (int nd = 0; nd < 2; nd++) {
                        int a = po * 2 + nd;
                        acc[a] = __builtin_amdgcn_mfma_f32_16x16x32_bf16(xh[nd], wh[po], acc[a], 0, 0, 0);
                        if (kp) {
                            acc[a] = __builtin_amdgcn_mfma_f32_16x16x32_bf16(xl[nd], wh[po], acc[a], 0, 0, 0);
                            acc[a] = __builtin_amdgcn_mfma_f32_16x16x32_bf16(xh[nd], wl[po], acc[a], 0, 0, 0);
                        }
                    }
                }
            }
        }
    }

    // epilogue: d = dbase + nd*16 + kb*4 + r -> dhi = dw*2+nd, dk = kb*4+r
#pragma unroll
    for (int po = 0; po < 4; po++) {
        int o = obase + po * 16 + lm;
        float bv = bias[o];
#pragma unroll
        for (int nd = 0; nd < 2; nd++) {
            int dhi = dw * 2 + nd;
#pragma unroll
            for (int r = 0; r < 4; r++) {
                int dk = kb * 4 + r;
                yh[(((size_t)b * 8 + dhi) * 256 + o) * 16 + dk] = acc[po * 2 + nd][r] + bv;
            }
        }
    }
}

// ---------------------------------------------------------------------------
// K3: fused topk + attention + context assembly.
//  One block per (b,h): stage K,V once; M = max-mean over sampled dots
//  (bitwise-identical math to R5 topk); stable rank-select top-30 in LDS;
//  vmean baseline; per-group (8 threads) softmax+PV with e-values in
//  registers and intra-group __shfl broadcast (no P array -> 46 KB LDS,
//  3 blocks/CU).  ctx written as bf16 hi/lo.
// ---------------------------------------------------------------------------
__global__ __launch_bounds__(256) void topk_attn_kernel(
    const float* __restrict__ q_h, const float* __restrict__ k_h,
    const float* __restrict__ v_h, const int* __restrict__ idxs,
    ushort* __restrict__ ctx_hi, ushort* __restrict__ ctx_lo)
{
    __shared__ float ks[S_ * 20];
    __shared__ float vs[S_ * 20];
    __shared__ float Marr[S_];
    __shared__ float qs[NT_][16];
    __shared__ float partial[16][17];
    __shared__ float vmean_s[16];
    __shared__ int sel_s[NT_];
    __shared__ int selflag[S_];
    __shared__ int cnt;

    int bh = blockIdx.x, b = bh >> 3, h = bh & 7;
    int tid = threadIdx.x;
    if (tid == 0) cnt = 0;
    selflag[tid] = 0;

    const float* kp = k_h + (size_t)bh * S_ * DK_;
    const float* vp = v_h + (size_t)bh * S_ * DK_;
    for (int idx = tid; idx < S_ * DK_; idx += 256) {
        int r = idx >> 4, c = idx & 15;
        ks[r * 20 + c] = kp[idx];
        vs[r * 20 + c] = vp[idx];
    }

    float qr[16];
    const float4* qp = (const float4*)(q_h + ((size_t)bh * S_ + tid) * DK_);
#pragma unroll
    for (int i = 0; i < 4; i++) {
        float4 t4 = qp[i];
        qr[4*i] = t4.x; qr[4*i+1] = t4.y; qr[4*i+2] = t4.z; qr[4*i+3] = t4.w;
    }
    int idxr[SK_];
    const int* ip = idxs + tid * SK_;
#pragma unroll
    for (int s = 0; s < SK_; s++) idxr[s] = ip[s];
    __syncthreads();   // ks/vs staged, cnt/selflag initialized

    // ---- M = max - mean over sampled dots (identical op order to R5) ----
    float mx = -1e30f, sm = 0.f;
#pragma unroll
    for (int s = 0; s < SK_; s++) {
        const float4* kr = (const float4*)(ks + idxr[s] * 20);
        float4 k0 = kr[0], k1 = kr[1], k2 = kr[2], k3 = kr[3];
        float d0 = qr[0]*k0.x, d1 = qr[1]*k0.y, d2 = qr[2]*k0.z, d3 = qr[3]*k0.w;
        d0 = fmaf(qr[4],  k1.x, d0); d1 = fmaf(qr[5],  k1.y, d1);
        d2 = fmaf(qr[6],  k1.z, d2); d3 = fmaf(qr[7],  k1.w, d3);
        d0 = fmaf(qr[8],  k2.x, d0); d1 = fmaf(qr[9],  k2.y, d1);
        d2 = fmaf(qr[10], k2.z, d2); d3 = fmaf(qr[11], k2.w, d3);
        d0 = fmaf(qr[12], k3.x, d0); d1 = fmaf(qr[13], k3.y, d1);
        d2 = fmaf(qr[14], k3.z, d2); d3 = fmaf(qr[15], k3.w, d3);
        float dot = (d0 + d1) + (d2 + d3);
        mx = fmaxf(mx, dot);
        sm += dot;
    }
    Marr[tid] = mx - sm * (1.0f / 30.0f);

    // vmean partials (vs is staged)
    {
        int dk = tid & 15, chunk = tid >> 4;
        float s = 0.f;
#pragma unroll
        for (int r = 0; r < 16; r++) s += vs[(chunk * 16 + r) * 20 + dk];
        partial[chunk][dk] = s;
    }
    __syncthreads();   // Marr, partial ready

    if (tid < 16) {
        float s = 0.f;
#pragma unroll
        for (int c = 0; c < 16; c++) s += partial[c][tid];
        vmean_s[tid] = s * (1.0f / 256.0f);
    }
    // stable rank-count selection (ties broken by index, = jax top_k)
    {
        float M = Marr[tid];
        int higher = 0;
        for (int j = 0; j < S_; j++) {
            float Mj = Marr[j];
            if (Mj > M || (Mj == M && j < tid)) higher++;
        }
        if (higher < NT_) {
            int slot = atomicAdd(&cnt, 1);
            sel_s[slot] = tid;
            selflag[tid] = 1;
        }
    }
    __syncthreads();   // sel_s, selflag, vmean_s ready

    for (int idx = tid; idx < NT_ * 16; idx += 256) {
        int u = idx >> 4, c = idx & 15;
        qs[u][c] = q_h[((size_t)bh * S_ + sel_s[u]) * DK_ + c];
    }
    __syncthreads();   // qs ready

    // baseline rows (non-selected): bf16 hi/lo of vmean
    if (!selflag[tid]) {
        alignas(16) ushort hh[16], ll[16];
#pragma unroll
        for (int i = 0; i < 16; i++) {
            float v = vmean_s[i];
            ushort hb = bf16_rne(v);
            hh[i] = hb;
            ll[i] = bf16_rne(v - bf16_to_f(hb));
        }
        size_t off = ((size_t)(b * S_ + tid)) * D_ + h * DK_;
        ((uint4*)(ctx_hi + off))[0] = ((uint4*)hh)[0];
        ((uint4*)(ctx_hi + off))[1] = ((uint4*)hh)[1];
        ((uint4*)(ctx_lo + off))[0] = ((uint4*)ll)[0];
        ((uint4*)(ctx_lo + off))[1] = ((uint4*)ll)[1];
    }

    // scores + softmax + PV: group g (8 threads) owns selected row g
    int g = tid >> 3, j = tid & 7;
    if (g < NT_) {
        float qreg[16];
        const float4* q4 = (const float4*)qs[g];
#pragma unroll
        for (int i = 0; i < 4; i++) {
            float4 t4 = q4[i];
            qreg[4*i] = t4.x; qreg[4*i+1] = t4.y; qreg[4*i+2] = t4.z; qreg[4*i+3] = t4.w;
        }
        float e[32];
        float mxs = -1e30f;
#pragma unroll
        for (int li = 0; li < 32; li++) {
            int l = j + li * 8;
            const float4* kr = (const float4*)(ks + l * 20);
            float4 k0 = kr[0], k1 = kr[1], k2 = kr[2], k3 = kr[3];
            float d0 = qreg[0]*k0.x, d1 = qreg[1]*k0.y, d2 = qreg[2]*k0.z, d3 = qreg[3]*k0.w;
            d0 = fmaf(qreg[4],  k1.x, d0); d1 = fmaf(qreg[5],  k1.y, d1);
            d2 = fmaf(qreg[6],  k1.z, d2); d3 = fmaf(qreg[7],  k1.w, d3);
            d0 = fmaf(qreg[8],  k2.x, d0); d1 = fmaf(qreg[9],  k2.y, d1);
            d2 = fmaf(qreg[10], k2.z, d2); d3 = fmaf(qreg[11], k2.w, d3);
            d0 = fmaf(qreg[12], k3.x, d0); d1 = fmaf(qreg[13], k3.y, d1);
            d2 = fmaf(qreg[14], k3.z, d2); d3 = fmaf(qreg[15], k3.w, d3);
            e[li] = ((d0 + d1) + (d2 + d3)) * 0.25f;   // 1/sqrt(16)
            mxs = fmaxf(mxs, e[li]);
        }
        mxs = fmaxf(mxs, __shfl_xor(mxs, 1));
        mxs = fmaxf(mxs, __shfl_xor(mxs, 2));
        mxs = fmaxf(mxs, __shfl_xor(mxs, 4));
        float se = 0.f;
#pragma unroll
        for (int li = 0; li < 32; li++) {
            e[li] = __expf(e[li] - mxs);
            se += e[li];
        }
        se += __shfl_xor(se, 1);
        se += __shfl_xor(se, 2);
        se += __shfl_xor(se, 4);
        float inv = 1.0f / se;

        int dk0 = j * 2;
        int gbase = tid & 56;              // lane & ~7 (group base within wave)
        float o0 = 0.f, o1 = 0.f;
        for (int li = 0; li < 32; li++) {
#pragma unroll
            for (int m = 0; m < 8; m++) {
                float p = __shfl(e[li], gbase | m);   // l = li*8 + m, ascending
                float2 vv = *(const float2*)(vs + (li * 8 + m) * 20 + dk0);
                o0 = fmaf(p, vv.x, o0);
                o1 = fmaf(p, vv.y, o1);
            }
        }
        int lrow = sel_s[g];
        float v0 = o0 * inv, v1 = o1 * inv;
        ushort h0 = bf16_rne(v0), h1 = bf16_rne(v1);
        ushort l0 = bf16_rne(v0 - bf16_to_f(h0));
        ushort l1 = bf16_rne(v1 - bf16_to_f(h1));
        size_t off = ((size_t)(b * S_ + lrow)) * D_ + h * DK_ + dk0;
        *(uint*)(ctx_hi + off) = (uint)h0 | ((uint)h1 << 16);
        *(uint*)(ctx_lo + off) = (uint)l0 | ((uint)l1 << 16);
    }
}

// ---------------------------------------------------------------------------
// K4: final linear as MFMA GEMM (unchanged from R3, passing).
// ---------------------------------------------------------------------------
__global__ __launch_bounds__(256) void linear_mfma_kernel(
    const ushort* __restrict__ ctx_hi, const ushort* __restrict__ ctx_lo,
    const ushort* __restrict__ w_hi, const ushort* __restrict__ w_lo,
    const float* __restrict__ bias, float* __restrict__ out)
{
    __shared__ ushort ahi[128 * 136];
    __shared__ ushort alo[128 * 136];

    int tid  = threadIdx.x;
    int lane = tid & 63, wid = tid >> 6;
    int lm = lane & 15, kb = lane >> 4;
    size_t rowbase = (size_t)blockIdx.x * 128;

    for (int idx = tid; idx < 2048; idx += 256) {
        int row = idx >> 4, c16 = idx & 15;
        short8 vh = *(const short8*)(ctx_hi + (rowbase + row) * 128 + c16 * 8);
        short8 vl = *(const short8*)(ctx_lo + (rowbase + row) * 128 + c16 * 8);
        *(short8*)(ahi + row * 136 + c16 * 8) = vh;
        *(short8*)(alo + row * 136 + c16 * 8) = vl;
    }
    __syncthreads();

    floatx4 acc[16];
#pragma unroll
    for (int i = 0; i < 16; i++) acc[i] = (floatx4){0.f, 0.f, 0.f, 0.f};

    const ushort* arow_h = ahi + (wid * 32 + lm) * 136 + kb * 8;
    const ushort* arow_l = alo + (wid * 32 + lm) * 136 + kb * 8;

#pragma unroll
    for (int kstep = 0; kstep < 4; kstep++) {
        short8 afh[2], afl[2];
#pragma unroll
        for (int mf = 0; mf < 2; mf++) {
            afh[mf] = *(const short8*)(arow_h + mf * 16 * 136 + kstep * 32);
            afl[mf] = *(const short8*)(arow_l + mf * 16 * 136 + kstep * 32);
        }
        short8 bfh[8], bfl[8];
#pragma unroll
        for (int nf = 0; nf < 8; nf++) {
            bfh[nf] = *(const short8*)(w_hi + (size_t)(nf * 16 + lm) * 128 + kstep * 32 + kb * 8);
            bfl[nf] = *(const short8*)(w_lo + (size_t)(nf * 16 + lm) * 128 + kstep * 32 + kb * 8);
        }
#pragma unroll
        for (int mf = 0; mf < 2; mf++) {
#pragma unroll
            for (int nf = 0; nf < 8; nf++) {
                int a = mf * 8 + nf;
                acc[a] = __builtin_amdgcn_mfma_f32_16x16x32_bf16(afh[mf], bfh[nf], acc[a], 0, 0, 0);
                acc[a] = __builtin_amdgcn_mfma_f32_16x16x32_bf16(afl[mf], bfh[nf], acc[a], 0, 0, 0);
                acc[a] = __builtin_amdgcn_mfma_f32_16x16x32_bf16(afh[mf], bfl[nf], acc[a], 0, 0, 0);
            }
        }
    }

#pragma unroll
    for (int nf = 0; nf < 8; nf++) {
        int col = nf * 16 + lm;
        float bv = bias[col];
#pragma unroll
        for (int mf = 0; mf < 2; mf++) {
#pragma unroll
            for (int r = 0; r < 4; r++) {
                int row = wid * 32 + mf * 16 + kb * 4 + r;
                out[(rowbase + row) * 128 + col] = acc[mf * 8 + nf][r] + bv;
            }
        }
    }
}

// ---------------------------------------------------------------------------
extern "C" void kernel_launch(void* const* d_in, const int* in_sizes, int n_in,
                              void* d_out, int out_size, void* d_ws, size_t ws_size,
                              hipStream_t stream)
{
    const float* query = (const float*)d_in[0];
    const float* key   = (const float*)d_in[1];
    const float* value = (const float*)d_in[2];
    const float* ckw   = (const float*)d_in[3];
    const float* ckb   = (const float*)d_in[4];
    const float* cvw   = (const float*)d_in[5];
    const float* cvb   = (const float*)d_in[6];
    const float* lw    = (const float*)d_in[7];
    const float* lb    = (const float*)d_in[8];
    const int*   isamp = (const int*)d_in[9];
    float* out = (float*)d_out;
    float* ws  = (float*)d_ws;

    const size_t NBSD = (size_t)B_ * S_ * D_;   // 4,194,304 floats
    float* q_h  = ws;                   // (B,H,S,DK)
    float* kbuf = ws + NBSD;            // overlaid by ctx hi/lo
    float* k_h  = ws + 2 * NBSD;        // (B,H,S,DK)
    float* v_h  = ws + 3 * NBSD;        // (B,H,S,DK)
    int*   sel  = (int*)(ws + 4 * NBSD);        // (unused, layout kept)
    ushort* wk_hi = (ushort*)(sel + B_ * H_ * NT_);   // [7][256][256] bf16 each
    ushort* wk_lo = wk_hi + 7 * 65536;
    ushort* wv_hi = wk_lo + 7 * 65536;
    ushort* lw_hi = wv_hi + 7 * 65536;  // [128][128]
    ushort* lw_lo = lw_hi + 16384;
    float*  trig  = (float*)(lw_lo + 16384);    // [256][64][2]
    ushort* khi_t = (ushort*)(trig + 32768);    // (B,D,S) bf16
    ushort* klo_t = khi_t + NBSD;
    ushort* vhi_t = klo_t + NBSD;
    ushort* ctx_hi = (ushort*)kbuf;
    ushort* ctx_lo = ctx_hi + NBSD;

    wprep_kernel<<<dim3(640), 256, 0, stream>>>(ckw, cvw, lw, wk_hi, wk_lo,
                                                wv_hi, lw_hi, lw_lo, trig);
    rotcvt_kernel<<<dim3(B_, 4), 256, 0, stream>>>(query, key, value, trig,
                                                   q_h, khi_t, klo_t, vhi_t);
    conv4_kernel<<<dim3(B_, 4, 2), 256, 0, stream>>>(khi_t, klo_t, vhi_t,
                                                     wk_hi, wk_lo, wv_hi,
                                                     ckb, cvb, k_h, v_h);
    topk_attn_kernel<<<dim3(B_ * H_), 256, 0, stream>>>(q_h, k_h, v_h, isamp,
                                                        ctx_hi, ctx_lo);
    linear_mfma_kernel<<<dim3(256), 256, 0, stream>>>(ctx_hi, ctx_lo, lw_hi,
                                                      lw_lo, lb, out);
}

// Round 7
// 279.919 us; speedup vs baseline: 1.2509x; 1.2509x over previous
//
#include <hip/hip_runtime.h>
#include <math.h>

// Problem constants
constexpr int B_  = 128;
constexpr int S_  = 256;
constexpr int D_  = 128;   // d_model
constexpr int H_  = 8;
constexpr int DK_ = 16;
constexpr int SK_ = 30;    // SAMPLE_K
constexpr int NT_ = 30;    // N_TOP

typedef short short8  __attribute__((ext_vector_type(8)));
typedef float floatx4 __attribute__((ext_vector_type(4)));

__device__ inline ushort bf16_rne(float f) {
    unsigned u = __float_as_uint(f);
    u += 0x7fffu + ((u >> 16) & 1u);
    return (ushort)(u >> 16);
}
__device__ inline float bf16_to_f(ushort h) {
    return __uint_as_float(((unsigned)h) << 16);
}

// ---------------------------------------------------------------------------
// K0: W prep + trig, t-major for coalesced writes.
//  (o,i,t) fp32 -> [t][o][i] bf16 hi/lo: thread = (t, oi) -> write address
//  == tid (fully coalesced 2B stores); reads are 7-strided 4B (L1-absorbed).
//  Same bf16_rne rounding as before -> bitwise-identical weights.
// ---------------------------------------------------------------------------
__global__ __launch_bounds__(256) void wprep_kernel(
    const float* __restrict__ wk, const float* __restrict__ wv,
    const float* __restrict__ lw,
    ushort* __restrict__ wk_hi, ushort* __restrict__ wk_lo,
    ushort* __restrict__ wv_hi,
    ushort* __restrict__ lw_hi, ushort* __restrict__ lw_lo,
    float* __restrict__ trig)
{
    int tid = blockIdx.x * 256 + threadIdx.x;   // grid 1920 -> 0..491519
    if (tid < 458752) {                         // 7*65536 conv weights
        int t  = tid >> 16;                     // 0..6
        int oi = tid & 65535;                   // o*256 + i
        float fk = wk[(size_t)oi * 7 + t];
        ushort hk = bf16_rne(fk);
        wk_hi[tid] = hk;                        // tid == t*65536 + oi
        wk_lo[tid] = bf16_rne(fk - bf16_to_f(hk));
        wv_hi[tid] = bf16_rne(wv[(size_t)oi * 7 + t]);
    } else if (tid < 475136) {                  // lin_w
        int ec = tid - 458752;                  // e*128 + c
        float f = lw[ec];
        ushort hi = bf16_rne(f);
        lw_hi[ec] = hi;
        lw_lo[ec] = bf16_rne(f - bf16_to_f(hi));
    } else {                                    // trig table (double)
        int t2 = tid - 475136;                  // 0..16383
        int f = t2 & 63, l = t2 >> 6;
        double freq = exp(((double)(-f) / 64.0) * 9.210340371976184); // ln(1e4)
        double ang  = (double)l * freq;
        trig[t2 * 2]     = (float)cos(ang);
        trig[t2 * 2 + 1] = (float)sin(ang);
    }
}

// ---------------------------------------------------------------------------
// K1: fused rotary + transpose + bf16 hi/lo convert, phase-split by grid z.
//  z=0: q rotary -> q_h (B,H,S,DK) fp32.
//  z=1: k rotary -> LDS -> (B,D,S) bf16 hi/lo.
//  z=2: v -> LDS -> (B,D,S) bf16 hi.
//  Same trig + rounding as R6 -> bitwise identical outputs.
// ---------------------------------------------------------------------------
__global__ __launch_bounds__(256) void rotcvt_kernel(
    const float* __restrict__ q, const float* __restrict__ k,
    const float* __restrict__ value, const float* __restrict__ trig,
    float* __restrict__ q_h,
    ushort* __restrict__ khi_t, ushort* __restrict__ klo_t,
    ushort* __restrict__ vhi_t)
{
    __shared__ float tile[64 * 132];   // 64 l x 128 d, pad 4
    int b  = blockIdx.x;
    int lc = blockIdx.y;               // l-chunk of 64
    int ph = blockIdx.z;               // 0=q, 1=k, 2=v
    int tid = threadIdx.x;

    if (ph == 0) {
        for (int s = tid; s < 2048; s += 256) {
            int l = s >> 5, c4 = s & 31;
            int lg = lc * 64 + l;
            float4 qv = *(const float4*)(q + (((size_t)b * 256) + lg) * 128 + c4 * 4);
            float4 tg = *(const float4*)(trig + ((size_t)lg * 64 + 2 * c4) * 2);
            float r0 = qv.x * tg.x - qv.y * tg.y;
            float i0 = qv.x * tg.y + qv.y * tg.x;
            float r1 = qv.z * tg.z - qv.w * tg.w;
            float i1 = qv.z * tg.w + qv.w * tg.z;
            int h = c4 >> 2, dk = (c4 & 3) * 4;
            *(float4*)(q_h + (((size_t)b * 8 + h) * 256 + lg) * 16 + dk) =
                make_float4(r0, i0, r1, i1);
        }
        return;
    }

    if (ph == 1) {
        for (int s = tid; s < 2048; s += 256) {
            int l = s >> 5, c4 = s & 31;
            int lg = lc * 64 + l;
            float4 kv = *(const float4*)(k + (((size_t)b * 256) + lg) * 128 + c4 * 4);
            float4 tg = *(const float4*)(trig + ((size_t)lg * 64 + 2 * c4) * 2);
            float r0 = kv.x * tg.x - kv.y * tg.y;
            float i0 = kv.x * tg.y + kv.y * tg.x;
            float r1 = kv.z * tg.z - kv.w * tg.w;
            float i1 = kv.z * tg.w + kv.w * tg.z;
            *(float4*)(tile + l * 132 + c4 * 4) = make_float4(r0, i0, r1, i1);
        }
        __syncthreads();
        int d = tid >> 1, half = tid & 1;
        alignas(16) ushort hh[32], ll[32];
#pragma unroll
        for (int j = 0; j < 32; j++) {
            float f = tile[(half * 32 + j) * 132 + d];
            ushort hb = bf16_rne(f);
            hh[j] = hb;
            ll[j] = bf16_rne(f - bf16_to_f(hb));
        }
        size_t off = (((size_t)b * 128) + d) * 256 + lc * 64 + half * 32;
#pragma unroll
        for (int m = 0; m < 4; m++) ((uint4*)(khi_t + off))[m] = ((uint4*)hh)[m];
#pragma unroll
        for (int m = 0; m < 4; m++) ((uint4*)(klo_t + off))[m] = ((uint4*)ll)[m];
        return;
    }

    // ph == 2: v
    for (int s = tid; s < 2048; s += 256) {
        int l = s >> 5, c4 = s & 31;
        *(float4*)(tile + l * 132 + c4 * 4) =
            *(const float4*)(value + (((size_t)b * 256) + lc * 64 + l) * 128 + c4 * 4);
    }
    __syncthreads();
    {
        int d = tid >> 1, half = tid & 1;
        alignas(16) ushort hh[32];
#pragma unroll
        for (int j = 0; j < 32; j++)
            hh[j] = bf16_rne(tile[(half * 32 + j) * 132 + d]);
        size_t off = (((size_t)b * 128) + d) * 256 + lc * 64 + half * 32;
#pragma unroll
        for (int m = 0; m < 4; m++) ((uint4*)(vhi_t + off))[m] = ((uint4*)hh)[m];
    }
}

// ---------------------------------------------------------------------------
// K2: fused causal-conv-as-MFMA-GEMM, v5: square 64x64 wave tiles.
//  Block = 64 d x 256 o (4 waves, wave = 64d x 64o, 4x4 16x16 frags).
//  Per K32-step per wave: 8 ds_read_b128 (A hi+lo) + 8 global 16B (B hi+lo,
//  disjoint o across waves -> zero W redundancy) -> 48 MFMAs (k) / 16 (v).
//  LDS = 70 rows x 72 x hi/lo = 20 KB; grid (128 b, 2 dblk, 2 kv) = 512.
//  Accumulation order per output (ic->ks->t, hh/lh/hl, same k-chunks)
//  identical to R5/R6 -> k_h bitwise unchanged -> top-k stable.
// ---------------------------------------------------------------------------
__global__ __launch_bounds__(256, 2) void conv5_kernel(
    const ushort* __restrict__ khi_t, const ushort* __restrict__ klo_t,
    const ushort* __restrict__ vhi_t,
    const ushort* __restrict__ wk_hi, const ushort* __restrict__ wk_lo,
    const ushort* __restrict__ wv_hi,
    const float* __restrict__ kbias, const float* __restrict__ vbias,
    float* __restrict__ k_h, float* __restrict__ v_h)
{
    constexpr int LI = 72;                 // 64 i + 8 pad (16B-aligned rows)
    __shared__ ushort xhi[70 * LI];
    __shared__ ushort xlo[70 * LI];

    const bool kp = (blockIdx.z == 0);
    const ushort* xg   = kp ? khi_t : vhi_t;
    const ushort* whi  = kp ? wk_hi : wv_hi;
    const float*  bias = kp ? kbias : vbias;
    float* yh          = kp ? k_h : v_h;

    int b    = blockIdx.x;
    int dblk = blockIdx.y;                 // 64-d slice
    int tid  = threadIdx.x;
    int lane = tid & 63, wid = tid >> 6;   // wave owns o-range wid*64
    int lm = lane & 15, kb = lane >> 4;
    int obase = wid * 64;

    floatx4 acc[16];                       // [po(4)][nd(4)]
#pragma unroll
    for (int i = 0; i < 16; i++) acc[i] = (floatx4){0.f, 0.f, 0.f, 0.f};

    const short8 zero8 = {0, 0, 0, 0, 0, 0, 0, 0};

    for (int ic = 0; ic < 4; ic++) {
        __syncthreads();
        // stage 70 d-rows (causal-shifted by 6) x 64 i: pure 16B copies
        for (int s = tid; s < 560; s += 256) {
            int r = s >> 3, p = s & 7;
            int gd = dblk * 64 - 6 + r;            // < 128 always
            size_t g = (((size_t)b * 128) + gd) * 256 + ic * 64 + p * 8;
            short8 vh = (gd >= 0) ? *(const short8*)(xg + g) : zero8;
            *(short8*)(xhi + r * LI + p * 8) = vh;
            if (kp) {
                short8 vl = (gd >= 0) ? *(const short8*)(klo_t + g) : zero8;
                *(short8*)(xlo + r * LI + p * 8) = vl;
            }
        }
        __syncthreads();
#pragma unroll
        for (int ks = 0; ks < 2; ks++) {
            int ibase = ic * 64 + ks * 32 + kb * 8;
#pragma unroll
            for (int t = 0; t < 7; t++) {
                short8 xh[4], xl[4];
#pragma unroll
                for (int nd = 0; nd < 4; nd++) {
                    int arow = (nd * 16 + lm + t) * LI + ks * 32 + kb * 8;
                    xh[nd] = *(const short8*)(xhi + arow);
                    if (kp) xl[nd] = *(const short8*)(xlo + arow);
                }
                short8 wh[4], wl[4];
#pragma unroll
                for (int po = 0; po < 4; po++) {
                    size_t woff = (size_t)t * 65536
                                + (size_t)(obase + po * 16 + lm) * 256 + ibase;
                    wh[po] = *(const short8*)(whi + woff);
                    if (kp) wl[po] = *(const short8*)(wk_lo + woff);
                }
#pragma unroll
                for (int po = 0; po < 4; po++) {
#pragma unroll
                    for (int nd = 0; nd < 4; nd++) {
                        int a = po * 4 + nd;
                        acc[a] = __builtin_amdgcn_mfma_f32_16x16x32_bf16(xh[nd], wh[po], acc[a], 0, 0, 0);
                        if (kp) {
                            acc[a] = __builtin_amdgcn_mfma_f32_16x16x32_bf16(xl[nd], wh[po], acc[a], 0, 0, 0);
                            acc[a] = __builtin_amdgcn_mfma_f32_16x16x32_bf16(xh[nd], wl[po], acc[a], 0, 0, 0);
                        }
                    }
                }
            }
        }
    }

    // epilogue: d = dblk*64 + nd*16 + kb*4 + r -> dhi = dblk*4+nd, dk = kb*4+r
#pragma unroll
    for (int po = 0; po < 4; po++) {
        int o = obase + po * 16 + lm;
        float bv = bias[o];
#pragma unroll
        for (int nd = 0; nd < 4; nd++) {
            int dhi = dblk * 4 + nd;
#pragma unroll
            for (int r = 0; r < 4; r++) {
                int dk = kb * 4 + r;
                yh[(((size_t)b * 8 + dhi) * 256 + o) * 16 + dk] = acc[po * 4 + nd][r] + bv;
            }
        }
    }
}

// ---------------------------------------------------------------------------
// K3: fused topk + attention + context assembly (unchanged from R6, passing).
// ---------------------------------------------------------------------------
__global__ __launch_bounds__(256) void topk_attn_kernel(
    const float* __restrict__ q_h, const float* __restrict__ k_h,
    const float* __restrict__ v_h, const int* __restrict__ idxs,
    ushort* __restrict__ ctx_hi, ushort* __restrict__ ctx_lo)
{
    __shared__ float ks[S_ * 20];
    __shared__ float vs[S_ * 20];
    __shared__ float Marr[S_];
    __shared__ float qs[NT_][16];
    __shared__ float partial[16][17];
    __shared__ float vmean_s[16];
    __shared__ int sel_s[NT_];
    __shared__ int selflag[S_];
    __shared__ int cnt;

    int bh = blockIdx.x, b = bh >> 3, h = bh & 7;
    int tid = threadIdx.x;
    if (tid == 0) cnt = 0;
    selflag[tid] = 0;

    const float* kp = k_h + (size_t)bh * S_ * DK_;
    const float* vp = v_h + (size_t)bh * S_ * DK_;
    for (int idx = tid; idx < S_ * DK_; idx += 256) {
        int r = idx >> 4, c = idx & 15;
        ks[r * 20 + c] = kp[idx];
        vs[r * 20 + c] = vp[idx];
    }

    float qr[16];
    const float4* qp = (const float4*)(q_h + ((size_t)bh * S_ + tid) * DK_);
#pragma unroll
    for (int i = 0; i < 4; i++) {
        float4 t4 = qp[i];
        qr[4*i] = t4.x; qr[4*i+1] = t4.y; qr[4*i+2] = t4.z; qr[4*i+3] = t4.w;
    }
    int idxr[SK_];
    const int* ip = idxs + tid * SK_;
#pragma unroll
    for (int s = 0; s < SK_; s++) idxr[s] = ip[s];
    __syncthreads();

    float mx = -1e30f, sm = 0.f;
#pragma unroll
    for (int s = 0; s < SK_; s++) {
        const float4* kr = (const float4*)(ks + idxr[s] * 20);
        float4 k0 = kr[0], k1 = kr[1], k2 = kr[2], k3 = kr[3];
        float d0 = qr[0]*k0.x, d1 = qr[1]*k0.y, d2 = qr[2]*k0.z, d3 = qr[3]*k0.w;
        d0 = fmaf(qr[4],  k1.x, d0); d1 = fmaf(qr[5],  k1.y, d1);
        d2 = fmaf(qr[6],  k1.z, d2); d3 = fmaf(qr[7],  k1.w, d3);
        d0 = fmaf(qr[8],  k2.x, d0); d1 = fmaf(qr[9],  k2.y, d1);
        d2 = fmaf(qr[10], k2.z, d2); d3 = fmaf(qr[11], k2.w, d3);
        d0 = fmaf(qr[12], k3.x, d0); d1 = fmaf(qr[13], k3.y, d1);
        d2 = fmaf(qr[14], k3.z, d2); d3 = fmaf(qr[15], k3.w, d3);
        float dot = (d0 + d1) + (d2 + d3);
        mx = fmaxf(mx, dot);
        sm += dot;
    }
    Marr[tid] = mx - sm * (1.0f / 30.0f);

    {
        int dk = tid & 15, chunk = tid >> 4;
        float s = 0.f;
#pragma unroll
        for (int r = 0; r < 16; r++) s += vs[(chunk * 16 + r) * 20 + dk];
        partial[chunk][dk] = s;
    }
    __syncthreads();

    if (tid < 16) {
        float s = 0.f;
#pragma unroll
        for (int c = 0; c < 16; c++) s += partial[c][tid];
        vmean_s[tid] = s * (1.0f / 256.0f);
    }
    {
        float M = Marr[tid];
        int higher = 0;
        for (int j = 0; j < S_; j++) {
            float Mj = Marr[j];
            if (Mj > M || (Mj == M && j < tid)) higher++;
        }
        if (higher < NT_) {
            int slot = atomicAdd(&cnt, 1);
            sel_s[slot] = tid;
            selflag[tid] = 1;
        }
    }
    __syncthreads();

    for (int idx = tid; idx < NT_ * 16; idx += 256) {
        int u = idx >> 4, c = idx & 15;
        qs[u][c] = q_h[((size_t)bh * S_ + sel_s[u]) * DK_ + c];
    }
    __syncthreads();

    if (!selflag[tid]) {
        alignas(16) ushort hh[16], ll[16];
#pragma unroll
        for (int i = 0; i < 16; i++) {
            float v = vmean_s[i];
            ushort hb = bf16_rne(v);
            hh[i] = hb;
            ll[i] = bf16_rne(v - bf16_to_f(hb));
        }
        size_t off = ((size_t)(b * S_ + tid)) * D_ + h * DK_;
        ((uint4*)(ctx_hi + off))[0] = ((uint4*)hh)[0];
        ((uint4*)(ctx_hi + off))[1] = ((uint4*)hh)[1];
        ((uint4*)(ctx_lo + off))[0] = ((uint4*)ll)[0];
        ((uint4*)(ctx_lo + off))[1] = ((uint4*)ll)[1];
    }

    int g = tid >> 3, j = tid & 7;
    if (g < NT_) {
        float qreg[16];
        const float4* q4 = (const float4*)qs[g];
#pragma unroll
        for (int i = 0; i < 4; i++) {
            float4 t4 = q4[i];
            qreg[4*i] = t4.x; qreg[4*i+1] = t4.y; qreg[4*i+2] = t4.z; qreg[4*i+3] = t4.w;
        }
        float e[32];
        float mxs = -1e30f;
#pragma unroll
        for (int li = 0; li < 32; li++) {
            int l = j + li * 8;
            const float4* kr = (const float4*)(ks + l * 20);
            float4 k0 = kr[0], k1 = kr[1], k2 = kr[2], k3 = kr[3];
            float d0 = qreg[0]*k0.x, d1 = qreg[1]*k0.y, d2 = qreg[2]*k0.z, d3 = qreg[3]*k0.w;
            d0 = fmaf(qreg[4],  k1.x, d0); d1 = fmaf(qreg[5],  k1.y, d1);
            d2 = fmaf(qreg[6],  k1.z, d2); d3 = fmaf(qreg[7],  k1.w, d3);
            d0 = fmaf(qreg[8],  k2.x, d0); d1 = fmaf(qreg[9],  k2.y, d1);
            d2 = fmaf(qreg[10], k2.z, d2); d3 = fmaf(qreg[11], k2.w, d3);
            d0 = fmaf(qreg[12], k3.x, d0); d1 = fmaf(qreg[13], k3.y, d1);
            d2 = fmaf(qreg[14], k3.z, d2); d3 = fmaf(qreg[15], k3.w, d3);
            e[li] = ((d0 + d1) + (d2 + d3)) * 0.25f;
            mxs = fmaxf(mxs, e[li]);
        }
        mxs = fmaxf(mxs, __shfl_xor(mxs, 1));
        mxs = fmaxf(mxs, __shfl_xor(mxs, 2));
        mxs = fmaxf(mxs, __shfl_xor(mxs, 4));
        float se = 0.f;
#pragma unroll
        for (int li = 0; li < 32; li++) {
            e[li] = __expf(e[li] - mxs);
            se += e[li];
        }
        se += __shfl_xor(se, 1);
        se += __shfl_xor(se, 2);
        se += __shfl_xor(se, 4);
        float inv = 1.0f / se;

        int dk0 = j * 2;
        int gbase = tid & 56;
        float o0 = 0.f, o1 = 0.f;
        for (int li = 0; li < 32; li++) {
#pragma unroll
            for (int m = 0; m < 8; m++) {
                float p = __shfl(e[li], gbase | m);
                float2 vv = *(const float2*)(vs + (li * 8 + m) * 20 + dk0);
                o0 = fmaf(p, vv.x, o0);
                o1 = fmaf(p, vv.y, o1);
            }
        }
        int lrow = sel_s[g];
        float v0 = o0 * inv, v1 = o1 * inv;
        ushort h0 = bf16_rne(v0), h1 = bf16_rne(v1);
        ushort l0 = bf16_rne(v0 - bf16_to_f(h0));
        ushort l1 = bf16_rne(v1 - bf16_to_f(h1));
        size_t off = ((size_t)(b * S_ + lrow)) * D_ + h * DK_ + dk0;
        *(uint*)(ctx_hi + off) = (uint)h0 | ((uint)h1 << 16);
        *(uint*)(ctx_lo + off) = (uint)l0 | ((uint)l1 << 16);
    }
}

// ---------------------------------------------------------------------------
// K4: final linear as MFMA GEMM, 512 blocks x 64 rows (2 blocks/CU).
// ---------------------------------------------------------------------------
__global__ __launch_bounds__(256) void linear_mfma_kernel(
    const ushort* __restrict__ ctx_hi, const ushort* __restrict__ ctx_lo,
    const ushort* __restrict__ w_hi, const ushort* __restrict__ w_lo,
    const float* __restrict__ bias, float* __restrict__ out)
{
    __shared__ ushort ahi[64 * 136];
    __shared__ ushort alo[64 * 136];

    int tid  = threadIdx.x;
    int lane = tid & 63, wid = tid >> 6;
    int lm = lane & 15, kb = lane >> 4;
    size_t rowbase = (size_t)blockIdx.x * 64;

    for (int idx = tid; idx < 1024; idx += 256) {
        int row = idx >> 4, c16 = idx & 15;
        short8 vh = *(const short8*)(ctx_hi + (rowbase + row) * 128 + c16 * 8);
        short8 vl = *(const short8*)(ctx_lo + (rowbase + row) * 128 + c16 * 8);
        *(short8*)(ahi + row * 136 + c16 * 8) = vh;
        *(short8*)(alo + row * 136 + c16 * 8) = vl;
    }
    __syncthreads();

    floatx4 acc[8];
#pragma unroll
    for (int i = 0; i < 8; i++) acc[i] = (floatx4){0.f, 0.f, 0.f, 0.f};

    const ushort* arow_h = ahi + (wid * 16 + lm) * 136 + kb * 8;
    const ushort* arow_l = alo + (wid * 16 + lm) * 136 + kb * 8;

#pragma unroll
    for (int kstep = 0; kstep < 4; kstep++) {
        short8 afh = *(const short8*)(arow_h + kstep * 32);
        short8 afl = *(const short8*)(arow_l + kstep * 32);
        short8 bfh[8], bfl[8];
#pragma unroll
        for (int nf = 0; nf < 8; nf++) {
            bfh[nf] = *(const short8*)(w_hi + (size_t)(nf * 16 + lm) * 128 + kstep * 32 + kb * 8);
            bfl[nf] = *(const short8*)(w_lo + (size_t)(nf * 16 + lm) * 128 + kstep * 32 + kb * 8);
        }
#pragma unroll
        for (int nf = 0; nf < 8; nf++) {
            acc[nf] = __builtin_amdgcn_mfma_f32_16x16x32_bf16(afh, bfh[nf], acc[nf], 0, 0, 0);
            acc[nf] = __builtin_amdgcn_mfma_f32_16x16x32_bf16(afl, bfh[nf], acc[nf], 0, 0, 0);
            acc[nf] = __builtin_amdgcn_mfma_f32_16x16x32_bf16(afh, bfl[nf], acc[nf], 0, 0, 0);
        }
    }

#pragma unroll
    for (int nf = 0; nf < 8; nf++) {
        int col = nf * 16 + lm;
        float bv = bias[col];
#pragma unroll
        for (int r = 0; r < 4; r++) {
            int row = wid * 16 + kb * 4 + r;
            out[(rowbase + row) * 128 + col] = acc[nf][r] + bv;
        }
    }
}

// ---------------------------------------------------------------------------
extern "C" void kernel_launch(void* const* d_in, const int* in_sizes, int n_in,
                              void* d_out, int out_size, void* d_ws, size_t ws_size,
                              hipStream_t stream)
{
    const float* query = (const float*)d_in[0];
    const float* key   = (const float*)d_in[1];
    const float* value = (const float*)d_in[2];
    const float* ckw   = (const float*)d_in[3];
    const float* ckb   = (const float*)d_in[4];
    const float* cvw   = (const float*)d_in[5];
    const float* cvb   = (const float*)d_in[6];
    const float* lw    = (const float*)d_in[7];
    const float* lb    = (const float*)d_in[8];
    const int*   isamp = (const int*)d_in[9];
    float* out = (float*)d_out;
    float* ws  = (float*)d_ws;

    const size_t NBSD = (size_t)B_ * S_ * D_;   // 4,194,304 floats
    float* q_h  = ws;                   // (B,H,S,DK)
    float* kbuf = ws + NBSD;            // overlaid by ctx hi/lo
    float* k_h  = ws + 2 * NBSD;        // (B,H,S,DK)
    float* v_h  = ws + 3 * NBSD;        // (B,H,S,DK)
    int*   sel  = (int*)(ws + 4 * NBSD);        // (unused, layout kept)
    ushort* wk_hi = (ushort*)(sel + B_ * H_ * NT_);   // [7][256][256] bf16 each
    ushort* wk_lo = wk_hi + 7 * 65536;
    ushort* wv_hi = wk_lo + 7 * 65536;
    ushort* lw_hi = wv_hi + 7 * 65536;  // [128][128]
    ushort* lw_lo = lw_hi + 16384;
    float*  trig  = (float*)(lw_lo + 16384);    // [256][64][2]
    ushort* khi_t = (ushort*)(trig + 32768);    // (B,D,S) bf16
    ushort* klo_t = khi_t + NBSD;
    ushort* vhi_t = klo_t + NBSD;
    ushort* ctx_hi = (ushort*)kbuf;
    ushort* ctx_lo = ctx_hi + NBSD;

    wprep_kernel<<<dim3(1920), 256, 0, stream>>>(ckw, cvw, lw, wk_hi, wk_lo,
                                                 wv_hi, lw_hi, lw_lo, trig);
    rotcvt_kernel<<<dim3(B_, 4, 3), 256, 0, stream>>>(query, key, value, trig,
                                                      q_h, khi_t, klo_t, vhi_t);
    conv5_kernel<<<dim3(B_, 2, 2), 256, 0, stream>>>(khi_t, klo_t, vhi_t,
                                                     wk_hi, wk_lo, wv_hi,
                                                     ckb, cvb, k_h, v_h);
    topk_attn_kernel<<<dim3(B_ * H_), 256, 0, stream>>>(q_h, k_h, v_h, isamp,
                                                        ctx_hi, ctx_lo);
    linear_mfma_kernel<<<dim3(512), 256, 0, stream>>>(ctx_hi, ctx_lo, lw_hi,
                                                      lw_lo, lb, out);
}